// Round 1
// baseline (396.085 us; speedup 1.0000x reference)
//
#include <hip/hip_runtime.h>

#define TSTEPS 500
#define NB 32
#define RS 1024
#define CD 5120
#define LT 400
#define NC 396
#define NEGF (-1e30f)
#define L2E 1.4426950408889634f
#define LN2f 0.6931471805599453f

// LDS-only barrier: drain LDS ops, do NOT drain in-flight global loads (vmcnt),
// so the depth-2 register prefetch pipeline survives the per-step barrier.
#define BARRIER() do {                                        \
    asm volatile("s_waitcnt lgkmcnt(0)" ::: "memory");        \
    __builtin_amdgcn_s_barrier();                             \
    asm volatile("" ::: "memory");                            \
} while (0)

// Issue global loads for time step tt into register set (M*, SS, VV).
#define PF(tt, M0, M1, M2, M3, M4, SS, VV) do {               \
    const float* p_ = scores + ((size_t)(tt) * NB + b) * (size_t)CD; \
    const float* pm_ = p_ + tid * 5;                          \
    M0 = pm_[0]; M1 = pm_[1]; M2 = pm_[2]; M3 = pm_[3]; M4 = pm_[4]; \
    if (is_ctc) { SS = p_[stay_off]; VV = p_[move_off]; }     \
} while (0)

// One scan step: trellis LSE over 5 sparse parents + banded CTC logaddexp.
#define STEP(rdbuf, wrbuf, M0, M1, M2, M3, M4, SS, VV) do {   \
    float t0 = M0 + my_a;                                     \
    float t1 = M1 + a_tr[rdbuf][q];                           \
    float t2 = M2 + a_tr[rdbuf][q + 256];                     \
    float t3 = M3 + a_tr[rdbuf][q + 512];                     \
    float t4 = M4 + a_tr[rdbuf][q + 768];                     \
    float mx = fmaxf(fmaxf(fmaxf(t0, t1), fmaxf(t2, t3)), t4);\
    float ssum = exp2f((t0 - mx) * L2E) + exp2f((t1 - mx) * L2E) \
               + exp2f((t2 - mx) * L2E) + exp2f((t3 - mx) * L2E) \
               + exp2f((t4 - mx) * L2E);                      \
    my_a = fmaf(log2f(ssum), LN2f, mx);                       \
    a_tr[wrbuf][tid] = my_a;                                  \
    if (is_ctc) {                                             \
        float x_  = a_ct[rdbuf][tid] + SS;                    \
        float am_ = a_ct[rdbuf][(tid == 0) ? 0 : (tid - 1)];  \
        float y_  = (tid >= 1) ? (am_ + VV) : NEGF;           \
        float m2_ = fmaxf(x_, y_);                            \
        float mn_ = fminf(x_, y_);                            \
        float e_  = exp2f((mn_ - m2_) * L2E);                 \
        a_ct[wrbuf][tid] = m2_ + LN2f * log2f(1.0f + e_);     \
    }                                                         \
} while (0)

extern "C" __global__ void __launch_bounds__(1024, 1)
ctc_crf_fused(const float* __restrict__ scores,
              const int* __restrict__ targets,
              const int* __restrict__ tlens,
              float* __restrict__ out)
{
    const int b = blockIdx.x;
    const int tid = threadIdx.x;

    __shared__ float a_tr[2][RS];     // trellis alpha ping-pong
    __shared__ float a_ct[2][NC];     // CTC alpha ping-pong
    __shared__ int   tg[LT];          // target bases (0..3)
    __shared__ float red[16];
    __shared__ float red2[16];

    if (tid < LT) {
        int v = targets[b * LT + tid] - 1;
        tg[tid] = v < 0 ? 0 : v;
    }
    a_tr[0][tid] = 0.0f;
    if (tid < NC) a_ct[0][tid] = (tid == 0) ? 0.0f : NEGF;
    __syncthreads();

    const bool is_ctc = (tid < NC);
    int stay_off = 0, move_off = 0;
    if (is_ctc) {
        int k = tg[tid];
        k = k * 4 + tg[tid + 1];
        k = k * 4 + tg[tid + 2];
        k = k * 4 + tg[tid + 3];
        k = k * 4 + tg[tid + 4];
        stay_off = k * 5;                                  // kmer * ALPHA_LEN
        move_off = (tid >= 1) ? (stay_off + tg[tid - 1] + 1) : 0;
    }
    __syncthreads();

    const int q = tid >> 2;
    float my_a = 0.0f;

    float mA0, mA1, mA2, mA3, mA4, mB0, mB1, mB2, mB3, mB4;
    float sA = 0.f, vA = 0.f, sB = 0.f, vB = 0.f;

    PF(0, mA0, mA1, mA2, mA3, mA4, sA, vA);
    PF(1, mB0, mB1, mB2, mB3, mB4, sB, vB);

    for (int t = 0; t < TSTEPS; t += 2) {
        STEP(0, 1, mA0, mA1, mA2, mA3, mA4, sA, vA);
        {
            int tp = t + 2; if (tp > TSTEPS - 1) tp = TSTEPS - 1;
            PF(tp, mA0, mA1, mA2, mA3, mA4, sA, vA);
        }
        BARRIER();
        STEP(1, 0, mB0, mB1, mB2, mB3, mB4, sB, vB);
        {
            int tq = t + 3; if (tq > TSTEPS - 1) tq = TSTEPS - 1;
            PF(tq, mB0, mB1, mB2, mB3, mB4, sB, vB);
        }
        BARRIER();
    }
    // Final trellis alphas live in my_a (== a_tr[0][tid]); CTC final in a_ct[0][*].

    // Block-wide LSE over 1024 trellis states.
    float wv = my_a;
    #pragma unroll
    for (int off = 32; off >= 1; off >>= 1)
        wv = fmaxf(wv, __shfl_xor(wv, off, 64));
    const int wave = tid >> 6;
    const int lane = tid & 63;
    if (lane == 0) red[wave] = wv;
    __syncthreads();
    float gmax = red[0];
    #pragma unroll
    for (int i = 1; i < 16; ++i) gmax = fmaxf(gmax, red[i]);
    float ex = exp2f((my_a - gmax) * L2E);
    #pragma unroll
    for (int off = 32; off >= 1; off >>= 1)
        ex += __shfl_xor(ex, off, 64);
    if (lane == 0) red2[wave] = ex;
    __syncthreads();

    if (tid == 0) {
        float tot = 0.0f;
        #pragma unroll
        for (int i = 0; i < 16; ++i) tot += red2[i];
        float logz_full = fmaf(log2f(tot), LN2f, gmax);
        int tl = tlens[b];                         // 400
        float ctcf = a_ct[0][tl - 5];              // alphaT[lengths-1], lengths = tl+1-5
        // normalized ctc logz = ctcf - logz_full; loss_b = -(that / tl)
        float loss_b = (logz_full - ctcf) / (float)tl;
        atomicAdd(out, loss_b * (1.0f / (float)NB));
    }
}

extern "C" void kernel_launch(void* const* d_in, const int* in_sizes, int n_in,
                              void* d_out, int out_size, void* d_ws, size_t ws_size,
                              hipStream_t stream) {
    const float* scores  = (const float*)d_in[0];
    const int*   targets = (const int*)d_in[1];
    const int*   tlens   = (const int*)d_in[2];
    float* out = (float*)d_out;

    hipMemsetAsync(out, 0, sizeof(float), stream);
    ctc_crf_fused<<<NB, RS, 0, stream>>>(scores, targets, tlens, out);
}

// Round 2
// 394.072 us; speedup vs baseline: 1.0051x; 1.0051x over previous
//
#include <hip/hip_runtime.h>

#define TSTEPS 500
#define NB 32
#define RS 1024
#define CD 5120
#define LT 400
#define NC 396
#define NEGF (-1e30f)
#define L2E 1.4426950408889634f
#define LN2f 0.6931471805599453f

// LDS-only barrier: drain LDS ops, do NOT drain in-flight global loads (vmcnt),
// so the deep register prefetch pipeline survives the per-step barrier.
#define BARRIER() do {                                        \
    asm volatile("s_waitcnt lgkmcnt(0)" ::: "memory");        \
    __builtin_amdgcn_s_barrier();                             \
    asm volatile("" ::: "memory");                            \
} while (0)

// Load 20 contiguous floats (4 states x 5 transition scores) as 5x dwordx4.
__device__ __forceinline__ void ldm(const float* __restrict__ p, float (&M)[20]) {
    const float4* p4 = (const float4*)p;
    float4 v0 = p4[0], v1 = p4[1], v2 = p4[2], v3 = p4[3], v4 = p4[4];
    M[0]=v0.x;  M[1]=v0.y;  M[2]=v0.z;  M[3]=v0.w;
    M[4]=v1.x;  M[5]=v1.y;  M[6]=v1.z;  M[7]=v1.w;
    M[8]=v2.x;  M[9]=v2.y;  M[10]=v2.z; M[11]=v2.w;
    M[12]=v3.x; M[13]=v3.y; M[14]=v3.z; M[15]=v3.w;
    M[16]=v4.x; M[17]=v4.y; M[18]=v4.z; M[19]=v4.w;
}

// One trellis step for 4 states r=4q..4q+3 (log2 domain). All 4 states share
// the same parent quad {q, q+256, q+512, q+768}.
__device__ __forceinline__ void tstep(const float (&M)[20], float (&ao)[4],
                                      const float* __restrict__ ar,
                                      float* __restrict__ aw, int q) {
    float p0 = ar[q], p1 = ar[q+256], p2 = ar[q+512], p3 = ar[q+768];
    float nw[4];
#pragma unroll
    for (int s = 0; s < 4; ++s) {
        float t0 = fmaf(M[5*s+0], L2E, ao[s]);
        float t1 = fmaf(M[5*s+1], L2E, p0);
        float t2 = fmaf(M[5*s+2], L2E, p1);
        float t3 = fmaf(M[5*s+3], L2E, p2);
        float t4 = fmaf(M[5*s+4], L2E, p3);
        float mx = fmaxf(fmaxf(fmaxf(t0,t1),t2), fmaxf(t3,t4));
        float e = exp2f(t0-mx)+exp2f(t1-mx)+exp2f(t2-mx)+exp2f(t3-mx)+exp2f(t4-mx);
        float r = mx + log2f(e);
        ao[s] = r; nw[s] = r;
    }
    *(float4*)(aw + 4*q) = make_float4(nw[0], nw[1], nw[2], nw[3]);
}

// CTC band: gather 7 stay + 7 move scores for this lane.
__device__ __forceinline__ void ldc(const float* __restrict__ p,
                                    const int (&so)[7], const int (&mo)[7],
                                    float (&S)[7], float (&V)[7]) {
#pragma unroll
    for (int k = 0; k < 7; ++k) { S[k] = p[so[k]]; V[k] = p[mo[k]]; }
}

// CTC step (log2 domain): alpha_new[i] = LAE(a[i]+s[i], a[i-1]+m[i]); neighbor
// across lanes via shfl_up. No barriers: one wave owns all 396 states.
__device__ __forceinline__ void cstep(const float (&S)[7], const float (&V)[7],
                                      float (&ac)[7], int lane) {
    float prev = __shfl_up(ac[6], 1, 64);
    float nw[7];
#pragma unroll
    for (int k = 0; k < 7; ++k) {
        float left = k ? ac[k-1] : prev;
        float x = fmaf(S[k], L2E, ac[k]);
        float y = fmaf(V[k], L2E, left);
        if (k == 0) y = (lane == 0) ? NEGF : y;
        float m2 = fmaxf(x, y);
        float d  = fminf(x, y) - m2;
        nw[k] = m2 + log2f(1.0f + exp2f(d));
    }
#pragma unroll
    for (int k = 0; k < 7; ++k) ac[k] = nw[k];
}

extern "C" __global__ void __launch_bounds__(256, 1)
ctc_crf(const float* __restrict__ scores, const int* __restrict__ targets,
        const int* __restrict__ tlens, float* __restrict__ out)
{
    const int tid = threadIdx.x;
    const size_t STP = (size_t)NB * CD;

    if (blockIdx.x < NB) {
        // ======================= trellis logZ =======================
        const int b = blockIdx.x;
        __shared__ float a_tr[2][RS];
        __shared__ float red[4], red2[4];

        *(float4*)&a_tr[0][4*tid] = make_float4(0.f, 0.f, 0.f, 0.f);
        __syncthreads();

        float M0[20], M1[20], M2[20], M3[20];
        const float* p0 = scores + (size_t)b*CD + (size_t)tid*20;
        const float* p1 = p0 + STP;
        const float* p2 = p0 + 2*STP;
        const float* p3 = p0 + 3*STP;
        ldm(p0, M0); ldm(p1, M1); ldm(p2, M2); ldm(p3, M3);

        float ao[4] = {0.f, 0.f, 0.f, 0.f};

        for (int t = 0; t < TSTEPS; t += 4) {
            tstep(M0, ao, a_tr[0], a_tr[1], tid);
            if (t+4 < TSTEPS) { p0 += 4*STP; ldm(p0, M0); }
            BARRIER();
            tstep(M1, ao, a_tr[1], a_tr[0], tid);
            if (t+5 < TSTEPS) { p1 += 4*STP; ldm(p1, M1); }
            BARRIER();
            tstep(M2, ao, a_tr[0], a_tr[1], tid);
            if (t+6 < TSTEPS) { p2 += 4*STP; ldm(p2, M2); }
            BARRIER();
            tstep(M3, ao, a_tr[1], a_tr[0], tid);
            if (t+7 < TSTEPS) { p3 += 4*STP; ldm(p3, M3); }
            BARRIER();
        }

        // Block-wide LSE over 1024 states (log2 domain).
        float m4 = fmaxf(fmaxf(ao[0], ao[1]), fmaxf(ao[2], ao[3]));
#pragma unroll
        for (int off = 32; off >= 1; off >>= 1)
            m4 = fmaxf(m4, __shfl_xor(m4, off, 64));
        const int w = tid >> 6, ln = tid & 63;
        if (ln == 0) red[w] = m4;
        __syncthreads();
        float g = fmaxf(fmaxf(red[0], red[1]), fmaxf(red[2], red[3]));
        float e4 = exp2f(ao[0]-g) + exp2f(ao[1]-g) + exp2f(ao[2]-g) + exp2f(ao[3]-g);
#pragma unroll
        for (int off = 32; off >= 1; off >>= 1)
            e4 += __shfl_xor(e4, off, 64);
        if (ln == 0) red2[w] = e4;
        __syncthreads();
        if (tid == 0) {
            float tot = red2[0] + red2[1] + red2[2] + red2[3];
            float logz_ln = LN2f * (g + log2f(tot));
            int tl = tlens[b];
            atomicAdd(out, logz_ln / ((float)tl * NB));
        }
    } else {
        // ======================= banded CTC logZ =======================
        if (tid >= 64) return;
        const int b = blockIdx.x - NB;
        const int lane = tid;

        // Target bases around this lane's 7 states (global idx 7*lane-1 .. +10).
        int tloc[12];
#pragma unroll
        for (int j = 0; j < 12; ++j) {
            int gi = 7*lane - 1 + j;
            gi = gi < 0 ? 0 : (gi > LT-1 ? LT-1 : gi);
            int v = targets[b*LT + gi] - 1;
            tloc[j] = v < 0 ? 0 : v;
        }
        int so[7], mo[7];
#pragma unroll
        for (int k = 0; k < 7; ++k) {
            int gi = 7*lane + k;
            if (gi < NC) {
                int K = tloc[k+1];
                K = K*4 + tloc[k+2];
                K = K*4 + tloc[k+3];
                K = K*4 + tloc[k+4];
                K = K*4 + tloc[k+5];
                so[k] = K*5;
                mo[k] = (gi >= 1) ? (so[k] + tloc[k] + 1) : 0;
            } else { so[k] = 0; mo[k] = 0; }
        }

        float ac[7];
#pragma unroll
        for (int k = 0; k < 7; ++k) ac[k] = (7*lane + k == 0) ? 0.0f : NEGF;

        const float* q0 = scores + (size_t)b*CD;
        const float* q1 = q0 + STP;
        const float* q2 = q0 + 2*STP;
        const float* q3 = q0 + 3*STP;
        float S0[7], V0[7], S1[7], V1[7], S2[7], V2[7], S3[7], V3[7];
        ldc(q0, so, mo, S0, V0); ldc(q1, so, mo, S1, V1);
        ldc(q2, so, mo, S2, V2); ldc(q3, so, mo, S3, V3);

        for (int t = 0; t < TSTEPS; t += 4) {
            cstep(S0, V0, ac, lane);
            if (t+4 < TSTEPS) { q0 += 4*STP; ldc(q0, so, mo, S0, V0); }
            cstep(S1, V1, ac, lane);
            if (t+5 < TSTEPS) { q1 += 4*STP; ldc(q1, so, mo, S1, V1); }
            cstep(S2, V2, ac, lane);
            if (t+6 < TSTEPS) { q2 += 4*STP; ldc(q2, so, mo, S2, V2); }
            cstep(S3, V3, ac, lane);
            if (t+7 < TSTEPS) { q3 += 4*STP; ldc(q3, so, mo, S3, V3); }
        }

        int tl = tlens[b];
        int idx = tl - 5;                 // alphaT[lengths-1], lengths = tl+1-5
        int srcLane = idx / 7, slot = idx % 7;
        float v = ac[0];
#pragma unroll
        for (int k = 1; k < 7; ++k) v = (slot == k) ? ac[k] : v;
        float r = __shfl(v, srcLane, 64);
        if (lane == 0)
            atomicAdd(out, -LN2f * r / ((float)tl * NB));
    }
}

extern "C" void kernel_launch(void* const* d_in, const int* in_sizes, int n_in,
                              void* d_out, int out_size, void* d_ws, size_t ws_size,
                              hipStream_t stream) {
    const float* scores  = (const float*)d_in[0];
    const int*   targets = (const int*)d_in[1];
    const int*   tlens   = (const int*)d_in[2];
    float* out = (float*)d_out;

    hipMemsetAsync(out, 0, sizeof(float), stream);
    ctc_crf<<<2*NB, 256, 0, stream>>>(scores, targets, tlens, out);
}